// Round 1
// 968.656 us; speedup vs baseline: 1.0667x; 1.0667x over previous
//
#include <hip/hip_runtime.h>
#include <math.h>

#define NB_B 32
#define NH 32
#define NKVH 8
#define GQ 4            // NH / NKVH
#define HD 128
#define BS 16
#define MAX_KV 4096
#define BPS 256         // MAX_KV / BS
#define NSPLIT 16
#define SPLIT_LEN 256   // MAX_KV / NSPLIT
#define ATT_SCALE 0.08838834764831845f

__device__ __forceinline__ float wave_max64(float v) {
#pragma unroll
  for (int off = 32; off > 0; off >>= 1) v = fmaxf(v, __shfl_xor(v, off, 64));
  return v;
}
__device__ __forceinline__ float wave_sum64(float v) {
#pragma unroll
  for (int off = 32; off > 0; off >>= 1) v += __shfl_xor(v, off, 64);
  return v;
}

// ws layout:
//   ws_o: [B][KVH][NSPLIT][GQ][HD]  float
//   ws_m: [B][KVH][NSPLIT][GQ]      float
//   ws_l: [B][KVH][NSPLIT][GQ]      float
// Combine only reads splits s < ceil(seqlen/SPLIT_LEN); empty splits never write
// (ws is poisoned every call, but poisoned entries are never read).
__launch_bounds__(256, 4)
__global__ void attn_split_kernel(const float* __restrict__ q,
                                  const float* __restrict__ kc,
                                  const float* __restrict__ vc,
                                  const int* __restrict__ seqlens,
                                  const int* __restrict__ btab,
                                  float* __restrict__ ws_o,
                                  float* __restrict__ ws_m,
                                  float* __restrict__ ws_l) {
  const int split = blockIdx.x;
  const int kvh   = blockIdx.y;
  const int b     = blockIdx.z;
  const int tid   = threadIdx.x;
  const int wave  = tid >> 6;
  const int lane  = tid & 63;

  const int seqlen = seqlens[b];
  const int start  = split * SPLIT_LEN;
  if (start >= seqlen) return;                 // combine skips this split
  const int end  = min(seqlen, start + SPLIT_LEN);
  const int midx = ((b * NKVH + kvh) * NSPLIT + split) * GQ;

  // p stored parity-interleaved: token c -> [(c&1)*32 + (c>>1)]
  __shared__ float p_par[4][GQ][64];
  __shared__ float wm[4][GQ];
  __shared__ float wl[4][GQ];
  __shared__ float wo[4][GQ][HD];

  const float* qbase = q + ((size_t)b * NH + (size_t)kvh * GQ) * HD;  // wave-uniform
  const int* bt = btab + (size_t)b * BPS;

  const int cbase = start + wave * 64;         // this wave's 64-token chunk
  const bool wvalid = (cbase < end);           // wave-uniform branch

  float m_h[GQ], l_h[GQ];
  float4 o4[GQ];
#pragma unroll
  for (int h = 0; h < GQ; ++h) {
    m_h[h] = -INFINITY;
    l_h[h] = 0.f;
    o4[h] = make_float4(0.f, 0.f, 0.f, 0.f);
  }

  if (wvalid) {
    // ---- phase 1: lane-per-token scores (single pass, no online rescale) ----
    const int tok = cbase + lane;
    const bool valid = (tok < end);
    const int blk = bt[tok >> 4];              // lane-varying (4 distinct values)
    const float* krow = kc + (((size_t)blk * BS + (tok & (BS - 1))) * NKVH + kvh) * HD;

    float s[GQ] = {0.f, 0.f, 0.f, 0.f};
#pragma unroll
    for (int dg = 0; dg < HD; dg += 4) {
      const float4 k4 = *(const float4*)(krow + dg);
#pragma unroll
      for (int h = 0; h < GQ; ++h) {
        const float* qh = qbase + h * HD + dg;  // uniform -> s_load
        s[h] = fmaf(qh[0], k4.x, s[h]);
        s[h] = fmaf(qh[1], k4.y, s[h]);
        s[h] = fmaf(qh[2], k4.z, s[h]);
        s[h] = fmaf(qh[3], k4.w, s[h]);
      }
    }

#pragma unroll
    for (int h = 0; h < GQ; ++h) {
      const float sv = valid ? s[h] * ATT_SCALE : -INFINITY;  // lane 0 always valid
      const float m  = wave_max64(sv);                        // finite
      const float p  = __expf(sv - m);                        // 0 for invalid lanes
      m_h[h] = m;
      l_h[h] = wave_sum64(p);
      p_par[wave][h][(lane & 1) * 32 + (lane >> 1)] = p;      // 2-way alias: free
    }
    __builtin_amdgcn_wave_barrier();  // wave-synchronous: order p write vs read

    // ---- phase 2: lane = (d-quad, token-parity) PV accumulate ----
    const int d4 = (lane & 31) * 4;
    const int tp = lane >> 5;
#pragma unroll
    for (int blk4 = 0; blk4 < 4; ++blk4) {     // 4 cache blocks per 64-token chunk
      const int t0 = cbase + blk4 * 16;
      if (t0 < end) {                          // wave-uniform guard
        const int pblk = bt[t0 >> 4];          // uniform -> s_load
        const float* vbase = vc + ((size_t)pblk * BS * NKVH + kvh) * HD;
#pragma unroll
        for (int ttg = 0; ttg < 16; ttg += 8) {
          float4 vv[4];
#pragma unroll
          for (int j = 0; j < 4; ++j)          // 2 tokens x 512B = 1KB per instr
            vv[j] = *(const float4*)(vbase + (size_t)(ttg + tp + 2 * j) * (NKVH * HD) + d4);
#pragma unroll
          for (int h = 0; h < GQ; ++h) {
            const float4 pq = *(const float4*)&p_par[wave][h][tp * 32 + blk4 * 8 + (ttg >> 1)];
            o4[h].x = fmaf(pq.x, vv[0].x, o4[h].x);
            o4[h].y = fmaf(pq.x, vv[0].y, o4[h].y);
            o4[h].z = fmaf(pq.x, vv[0].z, o4[h].z);
            o4[h].w = fmaf(pq.x, vv[0].w, o4[h].w);
            o4[h].x = fmaf(pq.y, vv[1].x, o4[h].x);
            o4[h].y = fmaf(pq.y, vv[1].y, o4[h].y);
            o4[h].z = fmaf(pq.y, vv[1].z, o4[h].z);
            o4[h].w = fmaf(pq.y, vv[1].w, o4[h].w);
            o4[h].x = fmaf(pq.z, vv[2].x, o4[h].x);
            o4[h].y = fmaf(pq.z, vv[2].y, o4[h].y);
            o4[h].z = fmaf(pq.z, vv[2].z, o4[h].z);
            o4[h].w = fmaf(pq.z, vv[2].w, o4[h].w);
            o4[h].x = fmaf(pq.w, vv[3].x, o4[h].x);
            o4[h].y = fmaf(pq.w, vv[3].y, o4[h].y);
            o4[h].z = fmaf(pq.w, vv[3].z, o4[h].z);
            o4[h].w = fmaf(pq.w, vv[3].w, o4[h].w);
          }
        }
      }
    }

    // merge the two token-parity partial sums (lanes l and l^32 share d4)
#pragma unroll
    for (int h = 0; h < GQ; ++h) {
      o4[h].x += __shfl_xor(o4[h].x, 32, 64);
      o4[h].y += __shfl_xor(o4[h].y, 32, 64);
      o4[h].z += __shfl_xor(o4[h].z, 32, 64);
      o4[h].w += __shfl_xor(o4[h].w, 32, 64);
    }
  }
  // invalid waves fall through with m=-inf, l=0, o=0 (MUST write zeros: the
  // cross-wave combine multiplies wo by exp(-inf - M) == 0, and 0*garbage
  // from poisoned/stale LDS could be NaN).

  if (lane == 0) {
#pragma unroll
    for (int h = 0; h < GQ; ++h) { wm[wave][h] = m_h[h]; wl[wave][h] = l_h[h]; }
  }
  if (lane < 32) {
#pragma unroll
    for (int h = 0; h < GQ; ++h) *(float4*)&wo[wave][h][4 * lane] = o4[h];
  }
  __syncthreads();

  // ---- cross-wave combine: 256 threads = 4 heads x 64 d-pairs ----
  const int h  = tid >> 6;
  const int dp = tid & 63;
  const float M = fmaxf(fmaxf(wm[0][h], wm[1][h]), fmaxf(wm[2][h], wm[3][h]));  // finite (wave 0 ran)
  float L = 0.f, ox = 0.f, oy = 0.f;
#pragma unroll
  for (int w = 0; w < 4; ++w) {
    const float f = __expf(wm[w][h] - M);  // exp(-inf)=0 for empty waves
    L  += wl[w][h] * f;
    ox += wo[w][h][2 * dp] * f;
    oy += wo[w][h][2 * dp + 1] * f;
  }
  const size_t oidx = (size_t)(midx + h) * HD;
  ws_o[oidx + 2 * dp]     = ox;
  ws_o[oidx + 2 * dp + 1] = oy;
  if (dp == 0) { ws_m[midx + h] = M; ws_l[midx + h] = L; }
}

__global__ void attn_combine_kernel(const float* __restrict__ ws_o,
                                    const float* __restrict__ ws_m,
                                    const float* __restrict__ ws_l,
                                    const int* __restrict__ seqlens,
                                    float* __restrict__ out) {
  const int bh = blockIdx.x;        // 0 .. B*H-1
  const int b  = bh / NH;
  const int hg = bh % NH;
  const int kvh = hg / GQ;
  const int h   = hg % GQ;
  const int d = threadIdx.x;        // 128
  const int nsp = (seqlens[b] + SPLIT_LEN - 1) / SPLIT_LEN;  // 1..16 valid splits
  const int base = ((b * NKVH + kvh) * NSPLIT) * GQ + h;

  float M = -INFINITY;
  for (int s = 0; s < nsp; ++s) M = fmaxf(M, ws_m[base + s * GQ]);
  float L = 0.f, acc = 0.f;
  for (int s = 0; s < nsp; ++s) {
    const float f = __expf(ws_m[base + s * GQ] - M);
    L   += ws_l[base + s * GQ] * f;
    acc += ws_o[(size_t)(base + s * GQ) * HD + d] * f;
  }
  out[(size_t)bh * HD + d] = acc / L;
}

extern "C" void kernel_launch(void* const* d_in, const int* in_sizes, int n_in,
                              void* d_out, int out_size, void* d_ws, size_t ws_size,
                              hipStream_t stream) {
  const float* q       = (const float*)d_in[0];
  const float* kc      = (const float*)d_in[1];
  const float* vc      = (const float*)d_in[2];
  const int*   seqlens = (const int*)d_in[3];
  const int*   btab    = (const int*)d_in[4];
  float* out = (float*)d_out;

  float* ws_o = (float*)d_ws;
  float* ws_m = ws_o + (size_t)NB_B * NKVH * NSPLIT * GQ * HD;
  float* ws_l = ws_m + (size_t)NB_B * NKVH * NSPLIT * GQ;

  dim3 grid1(NSPLIT, NKVH, NB_B);
  attn_split_kernel<<<grid1, 256, 0, stream>>>(q, kc, vc, seqlens, btab, ws_o, ws_m, ws_l);
  attn_combine_kernel<<<NB_B * NH, 128, 0, stream>>>(ws_o, ws_m, ws_l, seqlens, out);
}